// Round 18
// baseline (154.235 us; speedup 1.0000x reference)
//
#include <hip/hip_runtime.h>
#include <math.h>

#pragma clang fp contract(off)

#define NN 2
#define VV 2048
#define FF 2048
#define HH 384
#define WW 384
#define TH 1024
#define TW 1024
#define EPSD 1e-08
#define SLICES 8
#define FPS (FF / SLICES)                          // 256 faces per slice
#define REC 24                                     // doubles per face record
#define SETUP_BLOCKS ((NN * FF + 255) / 256)       // 16
#define CLEAR_BLOCKS ((NN * HH * WW + 255) / 256)  // 1152

// Separately-rounded fp32 multiply (blocks backend FMA fusion).
__device__ __forceinline__ float mulr(float a, float b) {
    float p = a * b;
    asm("" : "+v"(p));
    return p;
}

// f64 face record, 24 doubles:
// [0..8]   G:  b_i(px,py) = G[3i]*px + G[3i+1]*py + G[3i+2]   (raster)
// [9..11]  Zx,Zy,Zc: zinv(px,py) affine                        (raster+render)
// [12..14] Ux,Uy,Uc: numerator of gx                           (render)
// [15..17] Vx,Vy,Vc: numerator of gy                           (render)
// [18..23] pad
// cull record (float4 x4): bbox + sign-adjusted raw edge coeffs;
// !ok faces get C's = -3e30 so every tile rejects them.

// Fused: blocks [0, SETUP_BLOCKS) build face records; the rest clear keybuf.
__global__ __launch_bounds__(256) void setup_and_clear(
    const float* __restrict__ v, const float* __restrict__ campos,
    const float* __restrict__ camrot, const float* __restrict__ focal,
    const float* __restrict__ princpt, const int* __restrict__ vi,
    const float* __restrict__ vt, const int* __restrict__ vti,
    double* __restrict__ dface, float4* __restrict__ cull,
    unsigned long long* __restrict__ keybuf)
{
#pragma clang fp contract(off)
    if (blockIdx.x >= SETUP_BLOCKS) {
        int idx = (blockIdx.x - SETUP_BLOCKS) * 256 + threadIdx.x;
        if (idx < NN * HH * WW) keybuf[idx] = 0ull;
        return;
    }
    int t = blockIdx.x * blockDim.x + threadIdx.x;
    if (t >= NN * FF) return;
    int n = t / FF, f = t % FF;
    const float* cr = camrot + n * 9;
    const float* cp = campos + n * 3;
    const float* fo = focal + n * 4;
    const float* pp = princpt + n * 2;
    float X[3], Y[3], Z[3];
    for (int k = 0; k < 3; ++k) {
        int vid = vi[f * 3 + k];
        const float* vp = v + ((size_t)n * VV + vid) * 3;
        float d0 = vp[0] - cp[0];
        float d1 = vp[1] - cp[1];
        float d2 = vp[2] - cp[2];
        float c0 = (mulr(cr[0], d0) + mulr(cr[1], d1)) + mulr(cr[2], d2);
        float c1 = (mulr(cr[3], d0) + mulr(cr[4], d1)) + mulr(cr[5], d2);
        float c2 = (mulr(cr[6], d0) + mulr(cr[7], d1)) + mulr(cr[8], d2);
        float u = c0 / c2;
        float w = c1 / c2;
        X[k] = (mulr(fo[0], u) + mulr(fo[1], w)) + pp[0];
        Y[k] = (mulr(fo[2], u) + mulr(fo[3], w)) + pp[1];
        Z[k] = c2;
    }
    float area = mulr(X[1] - X[0], Y[2] - Y[0]) - mulr(Y[1] - Y[0], X[2] - X[0]);
    bool ok = fabsf(area) > 1e-9f;
    float inv = ok ? (1.0f / area) : __builtin_nanf("");
    float e0x = X[2] - X[1], e0y = Y[2] - Y[1];
    float e1x = X[0] - X[2], e1y = Y[0] - Y[2];
    float e2x = X[1] - X[0], e2y = Y[1] - Y[0];
    double invd = (double)inv;
    double e0xd = (double)e0x, e0yd = (double)e0y;
    double e1xd = (double)e1x, e1yd = (double)e1y;
    double e2xd = (double)e2x, e2yd = (double)e2y;
    double x0d = (double)X[0], y0d = (double)Y[0];
    double x1d = (double)X[1], y1d = (double)Y[1];
    double x2d = (double)X[2], y2d = (double)Y[2];
    double rz0 = 1.0 / (double)Z[0];
    double rz1 = 1.0 / (double)Z[1];
    double rz2 = 1.0 / (double)Z[2];
    double Gx0 = -e0yd * invd, Gy0 = e0xd * invd, Gc0 = (e0yd * x1d - e0xd * y1d) * invd;
    double Gx1 = -e1yd * invd, Gy1 = e1xd * invd, Gc1 = (e1yd * x2d - e1xd * y2d) * invd;
    double Gx2 = -e2yd * invd, Gy2 = e2xd * invd, Gc2 = (e2yd * x0d - e2xd * y0d) * invd;
    double Zx = Gx0 * rz0 + Gx1 * rz1 + Gx2 * rz2;
    double Zy = Gy0 * rz0 + Gy1 * rz1 + Gy2 * rz2;
    double Zc = Gc0 * rz0 + Gc1 * rz1 + Gc2 * rz2;
    int i0 = vti[f * 3 + 0], i1 = vti[f * 3 + 1], i2 = vti[f * 3 + 2];
    double u0d = (double)(2.0f * vt[i0 * 2 + 0] - 1.0f), v0d = (double)(2.0f * vt[i0 * 2 + 1] - 1.0f);
    double u1d = (double)(2.0f * vt[i1 * 2 + 0] - 1.0f), v1d = (double)(2.0f * vt[i1 * 2 + 1] - 1.0f);
    double u2d = (double)(2.0f * vt[i2 * 2 + 0] - 1.0f), v2d = (double)(2.0f * vt[i2 * 2 + 1] - 1.0f);
    double W0x = Gx0 * rz0, W0y = Gy0 * rz0, W0c = Gc0 * rz0;
    double W1x = Gx1 * rz1, W1y = Gy1 * rz1, W1c = Gc1 * rz1;
    double W2x = Gx2 * rz2, W2y = Gy2 * rz2, W2c = Gc2 * rz2;
    double Ux = (u0d * W0x + u1d * W1x) + u2d * W2x;
    double Uy = (u0d * W0y + u1d * W1y) + u2d * W2y;
    double Uc = (u0d * W0c + u1d * W1c) + u2d * W2c;
    double Vx = (v0d * W0x + v1d * W1x) + v2d * W2x;
    double Vy = (v0d * W0y + v1d * W1y) + v2d * W2y;
    double Vc = (v0d * W0c + v1d * W1c) + v2d * W2c;
    double* dd = dface + (size_t)t * REC;
    dd[0] = Gx0; dd[1] = Gy0; dd[2] = Gc0;
    dd[3] = Gx1; dd[4] = Gy1; dd[5] = Gc1;
    dd[6] = Gx2; dd[7] = Gy2; dd[8] = Gc2;
    dd[9] = Zx; dd[10] = Zy; dd[11] = Zc;
    dd[12] = Ux; dd[13] = Uy; dd[14] = Uc;
    dd[15] = Vx; dd[16] = Vy; dd[17] = Vc;
    dd[18] = 0.0; dd[19] = 0.0; dd[20] = 0.0;
    dd[21] = 0.0; dd[22] = 0.0; dd[23] = 0.0;
    // cull record
    float s = (area > 0.0f) ? 1.0f : -1.0f;
    float A0 = -e0y * s, B0 = e0x * s;
    float C0 = s * (float)(e0yd * x1d - e0xd * y1d);
    float A1 = -e1y * s, B1 = e1x * s;
    float C1 = s * (float)(e1yd * x2d - e1xd * y2d);
    float A2 = -e2y * s, B2 = e2x * s;
    float C2 = s * (float)(e2yd * x0d - e2xd * y0d);
    if (!ok) { C0 = -3e30f; C1 = -3e30f; C2 = -3e30f; }
    float xmn = fminf(fminf(X[0], X[1]), X[2]);
    float xmx = fmaxf(fmaxf(X[0], X[1]), X[2]);
    float ymn = fminf(fminf(Y[0], Y[1]), Y[2]);
    float ymx = fmaxf(fmaxf(Y[0], Y[1]), Y[2]);
    float4* cu = cull + (size_t)t * 4;
    cu[0] = make_float4(xmn, ymn, xmx, ymx);
    cu[1] = make_float4(A0, B0, C0, A1);
    cu[2] = make_float4(B1, C1, A2, B2);
    cu[3] = make_float4(C2, 0.0f, 0.0f, 0.0f);
}

__device__ __forceinline__ bool edge_keep(float A, float B, float C,
                                          float xlo, float xhi, float ylo, float yhi) {
    float m = A * ((A > 0.0f) ? xhi : xlo) + B * ((B > 0.0f) ? yhi : ylo) + C;
    return m >= -1.0f;   // margin ~0.01 px; f32 eval error << margin
}

// 16x16 px tile, 256 threads; blockIdx.z = n*SLICES+slice (faces f≡slice mod 8).
// Cull: thread t handles face slice + t*SLICES for all four 8x8 quadrants.
// Wave w evaluates quadrant w's list; winner via packed-key atomicMax.
__global__ __launch_bounds__(256) void raster(
    const double* __restrict__ dface, const float4* __restrict__ cull,
    unsigned long long* __restrict__ keybuf)
{
#pragma clang fp contract(fast)
    __shared__ int s_cnt[4];
    __shared__ int s_list[4][FPS];
    int nz = blockIdx.z;
    int n = nz / SLICES, slice = nz % SLICES;
    int tx0 = blockIdx.x * 16, ty0 = blockIdx.y * 16;
    int tid = threadIdx.x;
    int lane = tid & 63;
    int wv = tid >> 6;
    if (tid < 4) s_cnt[tid] = 0;
    __syncthreads();
    float xlo = (float)tx0, ylo = (float)ty0;
    {
        int f = slice + tid * SLICES;   // 256 threads cover all 256 slice faces
        const float4* cu = cull + ((size_t)n * FF + f) * 4;
        float4 bb = cu[0];
        if (bb.x <= xlo + 16.0f && bb.z >= xlo && bb.y <= ylo + 16.0f && bb.w >= ylo) {
            float4 c1 = cu[1], c2 = cu[2], c3 = cu[3];
            #pragma unroll
            for (int q = 0; q < 4; ++q) {
                float qxlo = xlo + (float)((q & 1) * 8), qxhi = qxlo + 8.0f;
                float qylo = ylo + (float)((q >> 1) * 8), qyhi = qylo + 8.0f;
                if (bb.x <= qxhi && bb.z >= qxlo && bb.y <= qyhi && bb.w >= qylo &&
                    edge_keep(c1.x, c1.y, c1.z, qxlo, qxhi, qylo, qyhi) &&
                    edge_keep(c1.w, c2.x, c2.y, qxlo, qxhi, qylo, qyhi) &&
                    edge_keep(c2.z, c2.w, c3.x, qxlo, qxhi, qylo, qyhi)) {
                    int p = atomicAdd(&s_cnt[q], 1);
                    s_list[q][p] = f;
                }
            }
        }
    }
    __syncthreads();
    int cnt = s_cnt[wv];
    int qx0 = tx0 + (wv & 1) * 8;
    int qy0 = ty0 + (wv >> 1) * 8;
    double px = (double)(qx0 + (lane & 7)) + 0.5;
    double py = (double)(qy0 + (lane >> 3)) + 0.5;
    unsigned long long best = 0ull;
    #pragma unroll 2
    for (int i = 0; i < cnt; ++i) {
        int fid = __builtin_amdgcn_readfirstlane(s_list[wv][i]);
        const double* g = dface + ((size_t)n * FF + fid) * REC;  // uniform → s_load
        double b0 = g[0] * px + (g[1] * py + g[2]);
        double b1 = g[3] * px + (g[4] * py + g[5]);
        double b2 = g[6] * px + (g[7] * py + g[8]);
        double zinv = g[9] * px + (g[10] * py + g[11]);
        if (b0 >= 0.0 && b1 >= 0.0 && b2 >= 0.0 && zinv > EPSD) {
            unsigned long long key =
                ((unsigned long long)__double_as_longlong(zinv) & ~0x7FFull)
                | (unsigned long long)(2047 - fid);
            if (key > best) best = key;
        }
    }
    if (best) {
        int x = qx0 + (lane & 7), y = qy0 + (lane >> 3);
        atomicMax(keybuf + ((size_t)n * HH + y) * WW + x, best);
    }
}

// render: f64 with precomputed affine uv numerators (round-17, proven at floor).
__global__ __launch_bounds__(256) void render(
    const double* __restrict__ dface, const unsigned long long* __restrict__ keybuf,
    const float* __restrict__ tex, float* __restrict__ out)
{
    int t = blockIdx.x * blockDim.x + threadIdx.x;
    if (t >= NN * HH * WW) return;
    int n = t / (HH * WW);
    int p = t % (HH * WW);
    int y = p / WW, x = p % WW;
    unsigned long long k = keybuf[t];
    int f = k ? (2047 - (int)(k & 0x7FFull)) : -1;
    size_t o0 = ((size_t)(n * 3 + 0) * HH + y) * WW + x;
    size_t o1 = ((size_t)(n * 3 + 1) * HH + y) * WW + x;
    size_t o2 = ((size_t)(n * 3 + 2) * HH + y) * WW + x;
    if (f < 0) {
        out[o0] = 0.0f; out[o1] = 0.0f; out[o2] = 0.0f;
        return;
    }
    const double* g = dface + ((size_t)n * FF + f) * REC;
    double px = (double)x + 0.5, py = (double)y + 0.5;
    double s = g[9] * px + (g[10] * py + g[11]);
    double zq = fmax(s, EPSD);
    double rzq = 1.0 / zq;                     // the ONE f64 division
    double gx = (g[12] * px + (g[13] * py + g[14])) * rzq;
    double gy = (g[15] * px + (g[16] * py + g[17])) * rzq;
    double ix = ((gx + 1.0) * (double)TW - 1.0) * 0.5;
    double iy = ((gy + 1.0) * (double)TH - 1.0) * 0.5;
    double fx0 = floor(ix), fy0 = floor(iy);
    double wx = ix - fx0, wy = iy - fy0;
    int x0 = min(max((int)fx0, 0), TW - 1);
    int x1 = min(max((int)fx0 + 1, 0), TW - 1);
    int y0 = min(max((int)fy0, 0), TH - 1);
    int y1 = min(max((int)fy0 + 1, 0), TH - 1);
    double omwx = 1.0 - wx, omwy = 1.0 - wy;
    #pragma unroll
    for (int c = 0; c < 3; ++c) {
        const float* tc = tex + ((size_t)n * 3 + c) * TH * TW;
        double g00 = (double)tc[(size_t)y0 * TW + x0];
        double g01 = (double)tc[(size_t)y0 * TW + x1];
        double g10 = (double)tc[(size_t)y1 * TW + x0];
        double g11 = (double)tc[(size_t)y1 * TW + x1];
        double val = (((g00 * omwx) * omwy + (g01 * wx) * omwy)
                      + (g10 * omwx) * wy) + (g11 * wx) * wy;
        size_t oo = (c == 0) ? o0 : ((c == 1) ? o1 : o2);
        out[oo] = (float)val;
    }
}

extern "C" void kernel_launch(void* const* d_in, const int* in_sizes, int n_in,
                              void* d_out, int out_size, void* d_ws, size_t ws_size,
                              hipStream_t stream) {
    const float* v = (const float*)d_in[0];
    const float* tex = (const float*)d_in[1];
    const float* campos = (const float*)d_in[2];
    const float* camrot = (const float*)d_in[3];
    const float* focal = (const float*)d_in[4];
    const float* princpt = (const float*)d_in[5];
    const float* vt = (const float*)d_in[6];
    const int* vi = (const int*)d_in[7];
    const int* vti = (const int*)d_in[8];
    float* out = (float*)d_out;

    char* ws = (char*)d_ws;
    double* dface = (double*)ws;                            // 4096*24*8 = 786432 B
    float4* cull = (float4*)(ws + 786432);                  // +262144 B
    unsigned long long* keybuf =
        (unsigned long long*)(ws + 786432 + 262144);        // +2359296 B

    setup_and_clear<<<dim3(SETUP_BLOCKS + CLEAR_BLOCKS), dim3(256), 0, stream>>>(
        v, campos, camrot, focal, princpt, vi, vt, vti, dface, cull, keybuf);
    raster<<<dim3(WW / 16, HH / 16, NN * SLICES), dim3(256), 0, stream>>>(
        dface, cull, keybuf);
    render<<<dim3((NN * HH * WW + 255) / 256), dim3(256), 0, stream>>>(
        dface, keybuf, tex, out);
}

// Round 19
// 146.668 us; speedup vs baseline: 1.0516x; 1.0516x over previous
//
#include <hip/hip_runtime.h>
#include <math.h>

#pragma clang fp contract(off)

#define NN 2
#define VV 2048
#define FF 2048
#define HH 384
#define WW 384
#define TH 1024
#define TW 1024
#define EPSD 1e-08
#define SLICES 16
#define FPS (FF / SLICES)                          // 128 faces per slice
#define SETUP_BLOCKS ((NN * FF + 255) / 256)       // 16
#define CLEAR_BLOCKS ((NN * HH * WW + 255) / 256)  // 1152

// Separately-rounded fp32 multiply (blocks backend FMA fusion).
__device__ __forceinline__ float mulr(float a, float b) {
    float p = a * b;
    asm("" : "+v"(p));
    return p;
}

// dface: 16 doubles/face (raster hot record, 128 B dense — round-16 layout):
//   [0..8] G (b_i affine), [9..11] Zx,Zy,Zc, [12..15] pad
// uvface: 8 doubles/face (render only): [0..2] Ux,Uy,Uc, [3..5] Vx,Vy,Vc
// cull: float4 x4 (bbox + sign-adjusted raw edge coeffs; !ok → C=-3e30)

__global__ __launch_bounds__(256) void setup_and_clear(
    const float* __restrict__ v, const float* __restrict__ campos,
    const float* __restrict__ camrot, const float* __restrict__ focal,
    const float* __restrict__ princpt, const int* __restrict__ vi,
    const float* __restrict__ vt, const int* __restrict__ vti,
    double* __restrict__ dface, double* __restrict__ uvface,
    float4* __restrict__ cull, unsigned long long* __restrict__ keybuf)
{
#pragma clang fp contract(off)
    if (blockIdx.x >= SETUP_BLOCKS) {
        int idx = (blockIdx.x - SETUP_BLOCKS) * 256 + threadIdx.x;
        if (idx < NN * HH * WW) keybuf[idx] = 0ull;
        return;
    }
    int t = blockIdx.x * blockDim.x + threadIdx.x;
    if (t >= NN * FF) return;
    int n = t / FF, f = t % FF;
    const float* cr = camrot + n * 9;
    const float* cp = campos + n * 3;
    const float* fo = focal + n * 4;
    const float* pp = princpt + n * 2;
    float X[3], Y[3], Z[3];
    for (int k = 0; k < 3; ++k) {
        int vid = vi[f * 3 + k];
        const float* vp = v + ((size_t)n * VV + vid) * 3;
        float d0 = vp[0] - cp[0];
        float d1 = vp[1] - cp[1];
        float d2 = vp[2] - cp[2];
        float c0 = (mulr(cr[0], d0) + mulr(cr[1], d1)) + mulr(cr[2], d2);
        float c1 = (mulr(cr[3], d0) + mulr(cr[4], d1)) + mulr(cr[5], d2);
        float c2 = (mulr(cr[6], d0) + mulr(cr[7], d1)) + mulr(cr[8], d2);
        float u = c0 / c2;
        float w = c1 / c2;
        X[k] = (mulr(fo[0], u) + mulr(fo[1], w)) + pp[0];
        Y[k] = (mulr(fo[2], u) + mulr(fo[3], w)) + pp[1];
        Z[k] = c2;
    }
    float area = mulr(X[1] - X[0], Y[2] - Y[0]) - mulr(Y[1] - Y[0], X[2] - X[0]);
    bool ok = fabsf(area) > 1e-9f;
    float inv = ok ? (1.0f / area) : __builtin_nanf("");
    float e0x = X[2] - X[1], e0y = Y[2] - Y[1];
    float e1x = X[0] - X[2], e1y = Y[0] - Y[2];
    float e2x = X[1] - X[0], e2y = Y[1] - Y[0];
    double invd = (double)inv;
    double e0xd = (double)e0x, e0yd = (double)e0y;
    double e1xd = (double)e1x, e1yd = (double)e1y;
    double e2xd = (double)e2x, e2yd = (double)e2y;
    double x0d = (double)X[0], y0d = (double)Y[0];
    double x1d = (double)X[1], y1d = (double)Y[1];
    double x2d = (double)X[2], y2d = (double)Y[2];
    double rz0 = 1.0 / (double)Z[0];
    double rz1 = 1.0 / (double)Z[1];
    double rz2 = 1.0 / (double)Z[2];
    double Gx0 = -e0yd * invd, Gy0 = e0xd * invd, Gc0 = (e0yd * x1d - e0xd * y1d) * invd;
    double Gx1 = -e1yd * invd, Gy1 = e1xd * invd, Gc1 = (e1yd * x2d - e1xd * y2d) * invd;
    double Gx2 = -e2yd * invd, Gy2 = e2xd * invd, Gc2 = (e2yd * x0d - e2xd * y0d) * invd;
    double Zx = Gx0 * rz0 + Gx1 * rz1 + Gx2 * rz2;
    double Zy = Gy0 * rz0 + Gy1 * rz1 + Gy2 * rz2;
    double Zc = Gc0 * rz0 + Gc1 * rz1 + Gc2 * rz2;
    double* dd = dface + (size_t)t * 16;
    dd[0] = Gx0; dd[1] = Gy0; dd[2] = Gc0;
    dd[3] = Gx1; dd[4] = Gy1; dd[5] = Gc1;
    dd[6] = Gx2; dd[7] = Gy2; dd[8] = Gc2;
    dd[9] = Zx; dd[10] = Zy; dd[11] = Zc;
    dd[12] = 0.0; dd[13] = 0.0; dd[14] = 0.0; dd[15] = 0.0;
    // render UV affine numerators (separate table, not touched by raster)
    int i0 = vti[f * 3 + 0], i1 = vti[f * 3 + 1], i2 = vti[f * 3 + 2];
    double u0d = (double)(2.0f * vt[i0 * 2 + 0] - 1.0f), v0d = (double)(2.0f * vt[i0 * 2 + 1] - 1.0f);
    double u1d = (double)(2.0f * vt[i1 * 2 + 0] - 1.0f), v1d = (double)(2.0f * vt[i1 * 2 + 1] - 1.0f);
    double u2d = (double)(2.0f * vt[i2 * 2 + 0] - 1.0f), v2d = (double)(2.0f * vt[i2 * 2 + 1] - 1.0f);
    double W0x = Gx0 * rz0, W0y = Gy0 * rz0, W0c = Gc0 * rz0;
    double W1x = Gx1 * rz1, W1y = Gy1 * rz1, W1c = Gc1 * rz1;
    double W2x = Gx2 * rz2, W2y = Gy2 * rz2, W2c = Gc2 * rz2;
    double* uv = uvface + (size_t)t * 8;
    uv[0] = (u0d * W0x + u1d * W1x) + u2d * W2x;
    uv[1] = (u0d * W0y + u1d * W1y) + u2d * W2y;
    uv[2] = (u0d * W0c + u1d * W1c) + u2d * W2c;
    uv[3] = (v0d * W0x + v1d * W1x) + v2d * W2x;
    uv[4] = (v0d * W0y + v1d * W1y) + v2d * W2y;
    uv[5] = (v0d * W0c + v1d * W1c) + v2d * W2c;
    uv[6] = 0.0; uv[7] = 0.0;
    // cull record
    float s = (area > 0.0f) ? 1.0f : -1.0f;
    float A0 = -e0y * s, B0 = e0x * s;
    float C0 = s * (float)(e0yd * x1d - e0xd * y1d);
    float A1 = -e1y * s, B1 = e1x * s;
    float C1 = s * (float)(e1yd * x2d - e1xd * y2d);
    float A2 = -e2y * s, B2 = e2x * s;
    float C2 = s * (float)(e2yd * x0d - e2xd * y0d);
    if (!ok) { C0 = -3e30f; C1 = -3e30f; C2 = -3e30f; }
    float xmn = fminf(fminf(X[0], X[1]), X[2]);
    float xmx = fmaxf(fmaxf(X[0], X[1]), X[2]);
    float ymn = fminf(fminf(Y[0], Y[1]), Y[2]);
    float ymx = fmaxf(fmaxf(Y[0], Y[1]), Y[2]);
    float4* cu = cull + (size_t)t * 4;
    cu[0] = make_float4(xmn, ymn, xmx, ymx);
    cu[1] = make_float4(A0, B0, C0, A1);
    cu[2] = make_float4(B1, C1, A2, B2);
    cu[3] = make_float4(C2, 0.0f, 0.0f, 0.0f);
}

__device__ __forceinline__ bool edge_keep(float A, float B, float C,
                                          float xlo, float xhi, float ylo, float yhi) {
    float m = A * ((A > 0.0f) ? xhi : xlo) + B * ((B > 0.0f) ? yhi : ylo) + C;
    return m >= -1.0f;   // margin ~0.01 px; f32 eval error << margin
}

// raster: byte-identical structure to round 16 (best: 48.5 µs).
// 16x16 tile, 256 threads; blockIdx.z = n*SLICES+slice; full-width cull
// (face tid&127, quadrant pair tid>>7); wave w evaluates quadrant w.
__global__ __launch_bounds__(256) void raster(
    const double* __restrict__ dface, const float4* __restrict__ cull,
    unsigned long long* __restrict__ keybuf)
{
#pragma clang fp contract(fast)
    __shared__ int s_cnt[4];
    __shared__ int s_list[4][FPS];
    int nz = blockIdx.z;
    int n = nz / SLICES, slice = nz % SLICES;
    int tx0 = blockIdx.x * 16, ty0 = blockIdx.y * 16;
    int tid = threadIdx.x;
    int lane = tid & 63;
    int wv = tid >> 6;
    if (tid < 4) s_cnt[tid] = 0;
    __syncthreads();
    float xlo = (float)tx0, ylo = (float)ty0;
    {
        int f = slice + (tid & 127) * SLICES;     // 128 faces, each by 2 threads
        int qbase = (tid >> 7) * 2;               // this thread: quadrants qbase, qbase+1
        const float4* cu = cull + ((size_t)n * FF + f) * 4;
        float4 bb = cu[0];
        if (bb.x <= xlo + 16.0f && bb.z >= xlo && bb.y <= ylo + 16.0f && bb.w >= ylo) {
            float4 c1 = cu[1], c2 = cu[2], c3 = cu[3];
            #pragma unroll
            for (int qq = 0; qq < 2; ++qq) {
                int q = qbase + qq;
                float qxlo = xlo + (float)((q & 1) * 8), qxhi = qxlo + 8.0f;
                float qylo = ylo + (float)((q >> 1) * 8), qyhi = qylo + 8.0f;
                if (bb.x <= qxhi && bb.z >= qxlo && bb.y <= qyhi && bb.w >= qylo &&
                    edge_keep(c1.x, c1.y, c1.z, qxlo, qxhi, qylo, qyhi) &&
                    edge_keep(c1.w, c2.x, c2.y, qxlo, qxhi, qylo, qyhi) &&
                    edge_keep(c2.z, c2.w, c3.x, qxlo, qxhi, qylo, qyhi)) {
                    int p = atomicAdd(&s_cnt[q], 1);
                    s_list[q][p] = f;
                }
            }
        }
    }
    __syncthreads();
    int cnt = s_cnt[wv];
    int qx0 = tx0 + (wv & 1) * 8;
    int qy0 = ty0 + (wv >> 1) * 8;
    double px = (double)(qx0 + (lane & 7)) + 0.5;
    double py = (double)(qy0 + (lane >> 3)) + 0.5;
    unsigned long long best = 0ull;
    #pragma unroll 2
    for (int i = 0; i < cnt; ++i) {
        int fid = __builtin_amdgcn_readfirstlane(s_list[wv][i]);
        const double* g = dface + ((size_t)n * FF + fid) * 16;  // uniform → s_load
        double b0 = g[0] * px + (g[1] * py + g[2]);
        double b1 = g[3] * px + (g[4] * py + g[5]);
        double b2 = g[6] * px + (g[7] * py + g[8]);
        double zinv = g[9] * px + (g[10] * py + g[11]);
        if (b0 >= 0.0 && b1 >= 0.0 && b2 >= 0.0 && zinv > EPSD) {
            unsigned long long key =
                ((unsigned long long)__double_as_longlong(zinv) & ~0x7FFull)
                | (unsigned long long)(2047 - fid);
            if (key > best) best = key;
        }
    }
    if (best) {
        int x = qx0 + (lane & 7), y = qy0 + (lane >> 3);
        atomicMax(keybuf + ((size_t)n * HH + y) * WW + x, best);
    }
}

// render: affine uv (round-17, proven at floor) + float2-vectorized texel pairs.
__global__ __launch_bounds__(256) void render(
    const double* __restrict__ dface, const double* __restrict__ uvface,
    const unsigned long long* __restrict__ keybuf,
    const float* __restrict__ tex, float* __restrict__ out)
{
    int t = blockIdx.x * blockDim.x + threadIdx.x;
    if (t >= NN * HH * WW) return;
    int n = t / (HH * WW);
    int p = t % (HH * WW);
    int y = p / WW, x = p % WW;
    unsigned long long k = keybuf[t];
    int f = k ? (2047 - (int)(k & 0x7FFull)) : -1;
    size_t o0 = ((size_t)(n * 3 + 0) * HH + y) * WW + x;
    size_t o1 = ((size_t)(n * 3 + 1) * HH + y) * WW + x;
    size_t o2 = ((size_t)(n * 3 + 2) * HH + y) * WW + x;
    if (f < 0) {
        out[o0] = 0.0f; out[o1] = 0.0f; out[o2] = 0.0f;
        return;
    }
    const double* g = dface + ((size_t)n * FF + f) * 16;
    const double* uv = uvface + ((size_t)n * FF + f) * 8;
    double px = (double)x + 0.5, py = (double)y + 0.5;
    double s = g[9] * px + (g[10] * py + g[11]);
    double zq = fmax(s, EPSD);
    double rzq = 1.0 / zq;                     // the ONE f64 division
    double gx = (uv[0] * px + (uv[1] * py + uv[2])) * rzq;
    double gy = (uv[3] * px + (uv[4] * py + uv[5])) * rzq;
    double ix = ((gx + 1.0) * (double)TW - 1.0) * 0.5;
    double iy = ((gy + 1.0) * (double)TH - 1.0) * 0.5;
    double fx0 = floor(ix), fy0 = floor(iy);
    double wx = ix - fx0, wy = iy - fy0;
    int x0 = min(max((int)fx0, 0), TW - 1);
    int x1 = min(max((int)fx0 + 1, 0), TW - 1);
    int y0 = min(max((int)fy0, 0), TH - 1);
    int y1 = min(max((int)fy0 + 1, 0), TH - 1);
    double omwx = 1.0 - wx, omwy = 1.0 - wy;
    bool pair = (x1 == x0 + 1);
    #pragma unroll
    for (int c = 0; c < 3; ++c) {
        const float* tc = tex + ((size_t)n * 3 + c) * TH * TW;
        float g00, g01, g10, g11;
        if (pair) {
            float2 r0 = *(const float2*)(tc + (size_t)y0 * TW + x0);
            float2 r1 = *(const float2*)(tc + (size_t)y1 * TW + x0);
            g00 = r0.x; g01 = r0.y; g10 = r1.x; g11 = r1.y;
        } else {
            g00 = tc[(size_t)y0 * TW + x0];
            g01 = tc[(size_t)y0 * TW + x1];
            g10 = tc[(size_t)y1 * TW + x0];
            g11 = tc[(size_t)y1 * TW + x1];
        }
        double val = ((((double)g00 * omwx) * omwy + ((double)g01 * wx) * omwy)
                      + ((double)g10 * omwx) * wy) + ((double)g11 * wx) * wy;
        size_t oo = (c == 0) ? o0 : ((c == 1) ? o1 : o2);
        out[oo] = (float)val;
    }
}

extern "C" void kernel_launch(void* const* d_in, const int* in_sizes, int n_in,
                              void* d_out, int out_size, void* d_ws, size_t ws_size,
                              hipStream_t stream) {
    const float* v = (const float*)d_in[0];
    const float* tex = (const float*)d_in[1];
    const float* campos = (const float*)d_in[2];
    const float* camrot = (const float*)d_in[3];
    const float* focal = (const float*)d_in[4];
    const float* princpt = (const float*)d_in[5];
    const float* vt = (const float*)d_in[6];
    const int* vi = (const int*)d_in[7];
    const int* vti = (const int*)d_in[8];
    float* out = (float*)d_out;

    char* ws = (char*)d_ws;
    double* dface = (double*)ws;                             // 4096*16*8 = 524288 B
    double* uvface = (double*)(ws + 524288);                 // 4096*8*8 = 262144 B
    float4* cull = (float4*)(ws + 524288 + 262144);          // +262144 B
    unsigned long long* keybuf =
        (unsigned long long*)(ws + 524288 + 262144 + 262144);  // +2359296 B

    setup_and_clear<<<dim3(SETUP_BLOCKS + CLEAR_BLOCKS), dim3(256), 0, stream>>>(
        v, campos, camrot, focal, princpt, vi, vt, vti, dface, uvface, cull, keybuf);
    raster<<<dim3(WW / 16, HH / 16, NN * SLICES), dim3(256), 0, stream>>>(
        dface, cull, keybuf);
    render<<<dim3((NN * HH * WW + 255) / 256), dim3(256), 0, stream>>>(
        dface, uvface, keybuf, tex, out);
}